// Round 1
// baseline (232.593 us; speedup 1.0000x reference)
//
#include <hip/hip_runtime.h>
#include <stdint.h>

// ---------------- problem constants ----------------
#define B_ROWS 65536
#define D_IN   784
#define H_DIM  256
#define L_LEAF 64
#define C_CLS  10
#define N_COMB 320          // H + L combined GEMM width
#define K_PAD  832          // 13 * 64, zero-padded K
#define BK     64
#define BM     64
#define NSTEP  13           // ceil(784/64)

#define GAP_THRESH 0.03f    // ~13 sigma of bf16 logit noise (rms ~0.0023 on the gap)

using f32x4   = __attribute__((ext_vector_type(4))) float;
using bf16x8  = __attribute__((ext_vector_type(8))) short;     // 8 bf16 in 4 VGPRs (guide §3)
using ushort4v = __attribute__((ext_vector_type(4))) unsigned short;
using ushort8v = __attribute__((ext_vector_type(8))) unsigned short;

// ---------------- ws layout (bytes) ----------------
#define O_FLAGCNT  0
#define O_CHOICES  4096                          // 65536 * 4 = 262144
#define O_FLAGROWS (4096 + 262144)               // 262144
#define O_WT       (4096 + 262144 + 262144)      // 320*832*2 = 532480
#define O_FEAT     (4096 + 262144 + 262144 + 532480)
#define WS_NEEDED  (O_FEAT + (size_t)B_ROWS * H_DIM * 2)

__device__ __forceinline__ unsigned short f2bf(float f) {
    union { float f; unsigned int u; } c; c.f = f;
    unsigned int u = c.u;
    return (unsigned short)((u + 0x7fffu + ((u >> 16) & 1u)) >> 16);   // RNE
}
__device__ __forceinline__ float bf2f(unsigned short u) {
    union { unsigned int u; float f; } c; c.u = ((unsigned int)u) << 16;
    return c.f;
}

// ---------------- K0: prep. Wt[n][k] = bf16( n<256 ? Wf[k][n] : Wr[k][n-256] ), k<784 else 0.
// grid = 65 blocks (5 n-tiles x 13 k-tiles), 256 threads
__global__ void k0_prep(const float* __restrict__ Wf, const float* __restrict__ Wr,
                        unsigned short* __restrict__ Wt, unsigned int* __restrict__ flagcnt) {
    if (blockIdx.x == 0 && threadIdx.x == 0) *flagcnt = 0u;
    __shared__ __align__(16) unsigned short tile[64 * 72];   // [nn][kk], row stride 72
    int bn = blockIdx.x % 5;
    int bk = blockIdx.x / 5;
    int t  = threadIdx.x;
    // phase 1: read 64k x 64n fp32 (coalesced over n), convert, LDS-transpose
    #pragma unroll
    for (int i = 0; i < 16; ++i) {
        int flat = i * 256 + t;
        int kk = flat >> 6, nn = flat & 63;
        int n = bn * 64 + nn;
        int k = bk * 64 + kk;
        float v = 0.f;
        if (k < D_IN) {
            v = (n < H_DIM) ? Wf[(size_t)k * H_DIM + n]
                            : Wr[(size_t)k * L_LEAF + (n - H_DIM)];
        }
        tile[nn * 72 + kk] = f2bf(v);
    }
    __syncthreads();
    // phase 2: write rows n (k-contiguous) to Wt
    #pragma unroll
    for (int i = 0; i < 2; ++i) {
        int flat = i * 256 + t;
        int nn = flat >> 3, kc = flat & 7;
        ushort8v v = *(const ushort8v*)(&tile[nn * 72 + kc * 8]);
        *(ushort8v*)(Wt + (size_t)(bn * 64 + nn) * K_PAD + bk * 64 + kc * 8) = v;
    }
}

// ---------------- K1: fused dual GEMM (features + router logits) + argmax/flag
// grid = 1024 blocks, 256 threads (4 waves). Wave = 32 rows x 160 cols (2 M-tiles x 10 N-tiles).
__global__ __launch_bounds__(256, 2) void k1_gemm(
    const float* __restrict__ x, const unsigned short* __restrict__ Wt,
    const float* __restrict__ bfv, const float* __restrict__ brv,
    unsigned short* __restrict__ feat, int* __restrict__ choices,
    unsigned int* __restrict__ flagcnt, int* __restrict__ flagrows)
{
    __shared__ __align__(16) unsigned short Al[64 * 72];    // [row][72], 64B data + pad (144B stride)
    __shared__ __align__(16) unsigned short Bl[320 * 72];   // [n][72]

    int t = threadIdx.x;
    int w = t >> 6, l = t & 63;
    int q = l >> 4, ic = l & 15;
    int bm0 = blockIdx.x * BM;
    int mrow0 = (w >> 1) * 32;       // wave row base within block
    int ncol0 = (w & 1) * 160;       // wave col base

    f32x4 acc[2][10];
    #pragma unroll
    for (int a = 0; a < 2; ++a)
        #pragma unroll
        for (int b = 0; b < 10; ++b)
            acc[a][b] = (f32x4){0.f, 0.f, 0.f, 0.f};

    for (int ts = 0; ts < NSTEP; ++ts) {
        int k0 = ts * BK;
        // ---- stage A: 64 rows x 64 k fp32 -> bf16 LDS (1024 float4 / 256 thr = 4 each)
        #pragma unroll
        for (int i = 0; i < 4; ++i) {
            int flat = i * 256 + t;
            int row = flat >> 4, kq = flat & 15;
            int kg = k0 + kq * 4;
            f32x4 v = (f32x4){0.f, 0.f, 0.f, 0.f};
            if (kg < D_IN) v = *(const f32x4*)(x + (size_t)(bm0 + row) * D_IN + kg);
            ushort4v h;
            h.x = f2bf(v.x); h.y = f2bf(v.y); h.z = f2bf(v.z); h.w = f2bf(v.w);
            *(ushort4v*)(&Al[row * 72 + kq * 4]) = h;
        }
        // ---- stage B: 320 n x 64 k bf16 (2560 ushort8 / 256 thr = 10 each)
        #pragma unroll
        for (int i = 0; i < 10; ++i) {
            int flat = i * 256 + t;
            int n = flat >> 3, kc = flat & 7;
            ushort8v v = *(const ushort8v*)(Wt + (size_t)n * K_PAD + k0 + kc * 8);
            *(ushort8v*)(&Bl[n * 72 + kc * 8]) = v;
        }
        __syncthreads();
        // ---- compute: 2 k-subtiles x (2 M x 10 N) MFMAs
        #pragma unroll
        for (int kk = 0; kk < 2; ++kk) {
            bf16x8 a0 = *(const bf16x8*)(&Al[(mrow0 +      ic) * 72 + kk * 32 + q * 8]);
            bf16x8 a1 = *(const bf16x8*)(&Al[(mrow0 + 16 + ic) * 72 + kk * 32 + q * 8]);
            #pragma unroll
            for (int nt = 0; nt < 10; ++nt) {
                bf16x8 b = *(const bf16x8*)(&Bl[(ncol0 + nt * 16 + ic) * 72 + kk * 32 + q * 8]);
                acc[0][nt] = __builtin_amdgcn_mfma_f32_16x16x32_bf16(a0, b, acc[0][nt], 0, 0, 0);
                acc[1][nt] = __builtin_amdgcn_mfma_f32_16x16x32_bf16(a1, b, acc[1][nt], 0, 0, 0);
            }
        }
        __syncthreads();
    }

    // ---- epilogue: features (cols < 256): relu + bf16 store
    #pragma unroll
    for (int nt = 0; nt < 10; ++nt) {
        int col = ncol0 + nt * 16 + ic;
        if (col < H_DIM) {
            float bias = bfv[col];
            #pragma unroll
            for (int mt = 0; mt < 2; ++mt) {
                #pragma unroll
                for (int i = 0; i < 4; ++i) {
                    int row = bm0 + mrow0 + mt * 16 + q * 4 + i;
                    float v = acc[mt][nt][i] + bias;
                    v = v > 0.f ? v : 0.f;
                    feat[(size_t)row * H_DIM + col] = f2bf(v);
                }
            }
        }
    }

    // ---- router: waves with ncol0==160 hold cols 256..319 in nt 6..9
    if (ncol0 == 160) {
        #pragma unroll
        for (int mt = 0; mt < 2; ++mt) {
            #pragma unroll
            for (int i = 0; i < 4; ++i) {
                float m1 = -1e30f, m2 = -1e30f;
                int a1 = 0;
                #pragma unroll
                for (int nt = 6; nt < 10; ++nt) {
                    int leaf = (nt - 6) * 16 + ic;
                    float v = acc[mt][nt][i] + brv[leaf];
                    if (v > m1 || (v == m1 && leaf < a1)) { m2 = m1; m1 = v; a1 = leaf; }
                    else if (v > m2) { m2 = v; }
                }
                // butterfly top-2 merge across the 16-lane group
                #pragma unroll
                for (int s = 1; s < 16; s <<= 1) {
                    float om1 = __shfl_xor(m1, s, 64);
                    float om2 = __shfl_xor(m2, s, 64);
                    int   oa1 = __shfl_xor(a1, s, 64);
                    bool take = (om1 > m1) || (om1 == m1 && oa1 < a1);
                    float nm2 = take ? fmaxf(om2, m1) : fmaxf(m2, om1);
                    m1 = take ? om1 : m1;
                    a1 = take ? oa1 : a1;
                    m2 = nm2;
                }
                if (ic == 0) {
                    int row = bm0 + mrow0 + mt * 16 + q * 4 + i;
                    choices[row] = a1;
                    if (m1 - m2 < GAP_THRESH) {
                        unsigned int idx = atomicAdd(flagcnt, 1u);
                        flagrows[idx] = row;
                    }
                }
            }
        }
    }
}

// ---------------- K2: exact fp32 router for flagged rows. 1 wave/block, lane = leaf.
__global__ void k2_exact(const float* __restrict__ x, const float* __restrict__ Wr,
                         const float* __restrict__ brv,
                         const unsigned int* __restrict__ flagcnt,
                         const int* __restrict__ flagrows, int* __restrict__ choices)
{
    unsigned int cnt = *flagcnt;
    int l = threadIdx.x;
    for (unsigned int i = blockIdx.x; i < cnt; i += gridDim.x) {
        int row = flagrows[i];
        const float* xr = x + (size_t)row * D_IN;
        float s0 = 0.f, s1 = 0.f, s2 = 0.f, s3 = 0.f;
        for (int k = 0; k < D_IN; k += 4) {
            f32x4 xv = *(const f32x4*)(xr + k);
            s0 = fmaf(xv.x, Wr[(size_t)(k + 0) * L_LEAF + l], s0);
            s1 = fmaf(xv.y, Wr[(size_t)(k + 1) * L_LEAF + l], s1);
            s2 = fmaf(xv.z, Wr[(size_t)(k + 2) * L_LEAF + l], s2);
            s3 = fmaf(xv.w, Wr[(size_t)(k + 3) * L_LEAF + l], s3);
        }
        float v = (s0 + s1) + (s2 + s3) + brv[l];
        int a = l;
        #pragma unroll
        for (int s = 1; s < 64; s <<= 1) {
            float ov = __shfl_xor(v, s, 64);
            int   oa = __shfl_xor(a, s, 64);
            if (ov > v || (ov == v && oa < a)) { v = ov; a = oa; }
        }
        if (l == 0) choices[row] = a;
    }
}

// ---------------- K3: per-row leaf matvec. 16-lane group per row, 16 rows/block.
// grid = 4096 blocks x 256 threads.
__global__ __launch_bounds__(256) void k3_leaf(
    const unsigned short* __restrict__ feat, const int* __restrict__ choices,
    const float* __restrict__ Wl, const float* __restrict__ blv,
    float* __restrict__ out)
{
    int t = threadIdx.x;
    int wv = t >> 6, l = t & 63;
    int g = l >> 4, i = l & 15;
    int row = blockIdx.x * 16 + wv * 4 + g;
    int leaf = choices[row];

    // 16 bf16 features per lane
    ushort8v f0 = *(const ushort8v*)(feat + (size_t)row * H_DIM + i * 16);
    ushort8v f1 = *(const ushort8v*)(feat + (size_t)row * H_DIM + i * 16 + 8);
    float fv[16];
    #pragma unroll
    for (int j = 0; j < 8; ++j) { fv[j] = bf2f(f0[j]); fv[8 + j] = bf2f(f1[j]); }

    const float* wlb = Wl + (size_t)leaf * (H_DIM * C_CLS) + (size_t)i * 16 * C_CLS;
    float acc[C_CLS];
    #pragma unroll
    for (int c = 0; c < C_CLS; ++c) acc[c] = 0.f;
    #pragma unroll
    for (int h = 0; h < 16; ++h) {
        #pragma unroll
        for (int c = 0; c < C_CLS; ++c)
            acc[c] = fmaf(fv[h], wlb[h * C_CLS + c], acc[c]);
    }
    #pragma unroll
    for (int s = 1; s < 16; s <<= 1) {
        #pragma unroll
        for (int c = 0; c < C_CLS; ++c) acc[c] += __shfl_xor(acc[c], s, 64);
    }
    if (i == 0) {
        #pragma unroll
        for (int c = 0; c < C_CLS; ++c)
            out[(size_t)row * C_CLS + c] = acc[c] + blv[leaf * C_CLS + c];
    }
}

// ---------------- launcher ----------------
extern "C" void kernel_launch(void* const* d_in, const int* in_sizes, int n_in,
                              void* d_out, int out_size, void* d_ws, size_t ws_size,
                              hipStream_t stream) {
    if (ws_size < WS_NEEDED) return;   // loud fail (output stays poisoned)

    const float* x   = (const float*)d_in[0];
    const float* Wf  = (const float*)d_in[1];
    const float* bfv = (const float*)d_in[2];
    const float* Wr  = (const float*)d_in[3];
    const float* brv = (const float*)d_in[4];
    const float* Wl  = (const float*)d_in[5];
    const float* blv = (const float*)d_in[6];
    float* out = (float*)d_out;

    char* ws = (char*)d_ws;
    unsigned int*   flagcnt  = (unsigned int*)(ws + O_FLAGCNT);
    int*            choices  = (int*)(ws + O_CHOICES);
    int*            flagrows = (int*)(ws + O_FLAGROWS);
    unsigned short* Wt       = (unsigned short*)(ws + O_WT);
    unsigned short* feat     = (unsigned short*)(ws + O_FEAT);

    hipLaunchKernelGGL(k0_prep, dim3(65), dim3(256), 0, stream, Wf, Wr, Wt, flagcnt);
    hipLaunchKernelGGL(k1_gemm, dim3(B_ROWS / BM), dim3(256), 0, stream,
                       x, Wt, bfv, brv, feat, choices, flagcnt, flagrows);
    hipLaunchKernelGGL(k2_exact, dim3(8192), dim3(64), 0, stream,
                       x, Wr, brv, flagcnt, flagrows, choices);
    hipLaunchKernelGGL(k3_leaf, dim3(B_ROWS / 16), dim3(256), 0, stream,
                       feat, choices, Wl, blv, out);
}

// Round 2
// 195.028 us; speedup vs baseline: 1.1926x; 1.1926x over previous
//
#include <hip/hip_runtime.h>
#include <stdint.h>

// ---------------- problem constants ----------------
#define B_ROWS 65536
#define D_IN   784
#define H_DIM  256
#define L_LEAF 64
#define C_CLS  10
#define NSTEP  13            // ceil(784/64) K-steps of 64
#define BTILE  40960         // 320 n * 64 k * 2B per K-step tile
#define GAP_THRESH 0.03f     // ~12 sigma of bf16 logit-gap noise

using f32x4    = __attribute__((ext_vector_type(4))) float;
using bf16x8   = __attribute__((ext_vector_type(8))) short;
using ushort8v = __attribute__((ext_vector_type(8))) unsigned short;
using ushort4v = __attribute__((ext_vector_type(4))) unsigned short;

// ---------------- ws layout (bytes) ----------------
#define O_FLAGCNT  0
#define O_CHOICES  4096
#define O_FLAGROWS (O_CHOICES + B_ROWS * 4)
#define O_WT       (O_FLAGROWS + B_ROWS * 4)
#define O_FEAT     (O_WT + NSTEP * BTILE)
#define O_WLB      (O_FEAT + (size_t)B_ROWS * H_DIM * 2)
#define WS_BASE    O_WLB
#define WS_FULL    (O_WLB + (size_t)L_LEAF * H_DIM * C_CLS * 2)

__device__ __forceinline__ unsigned short f2bf(float f) {
    union { float f; unsigned int u; } c; c.f = f;
    unsigned int u = c.u;
    return (unsigned short)((u + 0x7fffu + ((u >> 16) & 1u)) >> 16);   // RNE
}
__device__ __forceinline__ float bf2f(unsigned short u) {
    union { unsigned int u; float f; } c; c.u = ((unsigned int)u) << 16;
    return c.f;
}

__device__ __forceinline__ void gload_lds16(const void* g, void* l) {
    __builtin_amdgcn_global_load_lds(
        (const __attribute__((address_space(1))) unsigned int*)g,
        (__attribute__((address_space(3))) unsigned int*)l, 16, 0, 0);
}

// ---------------- K0: build swizzled B image. ----------------
// LDS-image byte (ts*40960 + n*128 + c4*16) holds 8 bf16 of column n,
// k = ts*64 + (c4 ^ (n&7))*8 .. +8   (zero-padded past 784).
// grid = 13 blocks x 256 thr (one block per K-step tile).
__global__ void k0_prep(const float* __restrict__ Wf, const float* __restrict__ Wr,
                        unsigned short* __restrict__ Wt, unsigned int* __restrict__ flagcnt) {
    if (blockIdx.x == 0 && threadIdx.x == 0) *flagcnt = 0u;
    const int ts = blockIdx.x;
    const int t  = threadIdx.x;
    #pragma unroll
    for (int i = 0; i < 10; ++i) {
        int id = i * 256 + t;          // 2560 chunks; n fastest for coalesced source reads
        int n  = id % 320;
        int c4 = id / 320;
        int ks = ts * 64 + ((c4 ^ (n & 7)) << 3);
        unsigned short v[8];
        #pragma unroll
        for (int j = 0; j < 8; ++j) {
            int k = ks + j;
            float f = 0.f;
            if (k < D_IN)
                f = (n < H_DIM) ? Wf[(size_t)k * H_DIM + n]
                                : Wr[(size_t)k * L_LEAF + (n - H_DIM)];
            v[j] = f2bf(f);
        }
        *(ushort8v*)((char*)Wt + (size_t)ts * BTILE + (size_t)(n * 8 + c4) * 16) = *(ushort8v*)v;
    }
}

// ---------------- K0b: Wl -> bf16 (optional, if ws permits) ----------------
__global__ void k0b_wl(const float* __restrict__ Wl, unsigned short* __restrict__ Wlb) {
    int i = (blockIdx.x * 256 + threadIdx.x) * 4;
    f32x4 v = *(const f32x4*)(Wl + i);
    ushort4v h; h.x = f2bf(v.x); h.y = f2bf(v.y); h.z = f2bf(v.z); h.w = f2bf(v.w);
    *(ushort4v*)(Wlb + i) = h;
}

// ---------------- K1: fused dual GEMM + argmax/flag ----------------
// grid = 1024 x 256 thr (4 waves). Wave = 16 rows x 320 cols; A reg-direct, B via
// global_load_lds double-buffer; 2-phase pipeline.
__global__ __launch_bounds__(256, 2) void k1_gemm(
    const float* __restrict__ x, const unsigned short* __restrict__ Wt,
    const float* __restrict__ bfv, const float* __restrict__ brv,
    unsigned short* __restrict__ feat, int* __restrict__ choices,
    unsigned int* __restrict__ flagcnt, int* __restrict__ flagrows)
{
    __shared__ __align__(16) unsigned short Bl[2][320 * 64];   // 2 x 40 KiB

    const int t = threadIdx.x, w = t >> 6, l = t & 63, q = l >> 4, ic = l & 15;
    const int bm0 = blockIdx.x * 64;
    const float* xrow = x + (size_t)(bm0 + w * 16 + ic) * D_IN;

    f32x4 acc[20];
    #pragma unroll
    for (int i = 0; i < 20; ++i) acc[i] = (f32x4){0.f, 0.f, 0.f, 0.f};

    // per-lane swizzled ds_read offsets (in shorts) for kk=0,1
    const int rb0 = ic * 64 + (((q    ) ^ (ic & 7)) << 3);
    const int rb1 = ic * 64 + (((q + 4) ^ (ic & 7)) << 3);

    // ---- prologue: stage ts=0, load A(ts=0)
    #pragma unroll
    for (int i = 0; i < 10; ++i) {
        int cid = i * 256 + t;
        gload_lds16((const char*)Wt + cid * 16, (char*)&Bl[0][0] + cid * 16);
    }
    f32x4 an[4];
    #pragma unroll
    for (int kk = 0; kk < 2; ++kk) {
        int kg = kk * 32 + q * 8;
        an[2 * kk]     = *(const f32x4*)(xrow + kg);
        an[2 * kk + 1] = *(const f32x4*)(xrow + kg + 4);
    }
    __syncthreads();

    int cur = 0;
    for (int ts = 0; ts < NSTEP; ++ts) {
        // ---- stage next B tile (direct to LDS, stays in flight until barrier)
        if (ts + 1 < NSTEP) {
            const char* src = (const char*)Wt + (size_t)(ts + 1) * BTILE;
            char* dst = (char*)&Bl[cur ^ 1][0];
            #pragma unroll
            for (int i = 0; i < 10; ++i) {
                int cid = i * 256 + t;
                gload_lds16(src + cid * 16, dst + cid * 16);
            }
        }
        f32x4 ac0 = an[0], ac1 = an[1], ac2 = an[2], ac3 = an[3];
        // ---- prefetch A for ts+1 (tail chunks fully OOB are zeroed; B pad is 0 anyway)
        if (ts + 1 < NSTEP) {
            #pragma unroll
            for (int kk = 0; kk < 2; ++kk) {
                int kg = (ts + 1) * 64 + kk * 32 + q * 8;
                if (kg + 8 <= D_IN) {
                    an[2 * kk]     = *(const f32x4*)(xrow + kg);
                    an[2 * kk + 1] = *(const f32x4*)(xrow + kg + 4);
                } else {
                    an[2 * kk]     = (f32x4){0.f, 0.f, 0.f, 0.f};
                    an[2 * kk + 1] = (f32x4){0.f, 0.f, 0.f, 0.f};
                }
            }
        }
        // ---- convert current A to bf16 fragments
        bf16x8 af0, af1;
        #pragma unroll
        for (int j = 0; j < 4; ++j) {
            af0[j]     = (short)f2bf(ac0[j]);
            af0[4 + j] = (short)f2bf(ac1[j]);
            af1[j]     = (short)f2bf(ac2[j]);
            af1[4 + j] = (short)f2bf(ac3[j]);
        }
        // ---- MFMA: 2 kk x 20 nt
        const unsigned short* Bc = &Bl[cur][0];
        #pragma unroll
        for (int nt = 0; nt < 20; ++nt) {
            bf16x8 b = *(const bf16x8*)(Bc + nt * 1024 + rb0);
            acc[nt] = __builtin_amdgcn_mfma_f32_16x16x32_bf16(af0, b, acc[nt], 0, 0, 0);
        }
        #pragma unroll
        for (int nt = 0; nt < 20; ++nt) {
            bf16x8 b = *(const bf16x8*)(Bc + nt * 1024 + rb1);
            acc[nt] = __builtin_amdgcn_mfma_f32_16x16x32_bf16(af1, b, acc[nt], 0, 0, 0);
        }
        __syncthreads();       // drains stage vmcnt + read lgkm; next buf ready
        cur ^= 1;
    }

    // ---- epilogue: features (nt 0..15)
    #pragma unroll
    for (int nt = 0; nt < 16; ++nt) {
        int col = nt * 16 + ic;
        float bias = bfv[col];
        #pragma unroll
        for (int i = 0; i < 4; ++i) {
            int row = bm0 + w * 16 + q * 4 + i;
            float v = acc[nt][i] + bias;
            v = v > 0.f ? v : 0.f;
            feat[(size_t)row * H_DIM + col] = f2bf(v);
        }
    }
    // ---- router (nt 16..19): top-2 + argmax + flag
    #pragma unroll
    for (int i = 0; i < 4; ++i) {
        float m1 = -1e30f, m2 = -1e30f;
        int a1 = 0;
        #pragma unroll
        for (int nt = 16; nt < 20; ++nt) {
            int leaf = (nt - 16) * 16 + ic;
            float v = acc[nt][i] + brv[leaf];
            if (v > m1) { m2 = m1; m1 = v; a1 = leaf; }
            else if (v > m2) { m2 = v; }
        }
        #pragma unroll
        for (int s = 1; s < 16; s <<= 1) {
            float om1 = __shfl_xor(m1, s, 64);
            float om2 = __shfl_xor(m2, s, 64);
            int   oa1 = __shfl_xor(a1, s, 64);
            bool take = (om1 > m1) || (om1 == m1 && oa1 < a1);
            float nm2 = take ? fmaxf(om2, m1) : fmaxf(m2, om1);
            m1 = take ? om1 : m1;
            a1 = take ? oa1 : a1;
            m2 = nm2;
        }
        if (ic == 0) {
            int row = bm0 + w * 16 + q * 4 + i;
            choices[row] = a1;
            if (m1 - m2 < GAP_THRESH) {
                unsigned int idx = atomicAdd(flagcnt, 1u);
                flagrows[idx] = row;
            }
        }
    }
}

// ---------------- K2: exact fp32 router, Wr tiles shared via LDS ----------------
// block = 256 thr (4 waves) handles 4 flagged rows; lane = leaf.
__global__ __launch_bounds__(256) void k2_exact(
    const float* __restrict__ x, const float* __restrict__ Wr,
    const float* __restrict__ brv, const unsigned int* __restrict__ flagcnt,
    const int* __restrict__ flagrows, int* __restrict__ choices)
{
    __shared__ float wl[64 * 64];   // [kk][l]
    __shared__ float xl[4][64];
    const unsigned int cnt = *flagcnt;
    const int t = threadIdx.x, w = t >> 6, l = t & 63;
    for (unsigned int base = blockIdx.x * 4u; base < cnt; base += gridDim.x * 4u) {
        unsigned int ri = base + w;
        int row = (ri < cnt) ? flagrows[ri] : 0;
        const float* xr = x + (size_t)row * D_IN;
        float s0 = 0.f, s1 = 0.f, s2 = 0.f, s3 = 0.f;
        for (int kt = 0; kt < NSTEP; ++kt) {
            int k0 = kt * 64;
            #pragma unroll
            for (int i = 0; i < 4; ++i) {
                int flat = i * 256 + t;
                int kk = flat >> 4, lq = (flat & 15) * 4;
                int kg = k0 + kk;
                f32x4 v = (f32x4){0.f, 0.f, 0.f, 0.f};
                if (kg < D_IN) v = *(const f32x4*)(Wr + (size_t)kg * L_LEAF + lq);
                *(f32x4*)&wl[kk * 64 + lq] = v;
            }
            xl[w][l] = (k0 + l < D_IN) ? xr[k0 + l] : 0.f;
            __syncthreads();
            #pragma unroll
            for (int kk = 0; kk < 64; kk += 4) {
                s0 = fmaf(xl[w][kk    ], wl[(kk    ) * 64 + l], s0);
                s1 = fmaf(xl[w][kk + 1], wl[(kk + 1) * 64 + l], s1);
                s2 = fmaf(xl[w][kk + 2], wl[(kk + 2) * 64 + l], s2);
                s3 = fmaf(xl[w][kk + 3], wl[(kk + 3) * 64 + l], s3);
            }
            __syncthreads();
        }
        float v = (s0 + s1) + (s2 + s3) + brv[l];
        int a = l;
        #pragma unroll
        for (int st = 1; st < 64; st <<= 1) {
            float ov = __shfl_xor(v, st, 64);
            int   oa = __shfl_xor(a, st, 64);
            if (ov > v || (ov == v && oa < a)) { v = ov; a = oa; }
        }
        if (l == 0 && ri < cnt) choices[row] = a;
    }
}

// ---------------- K3: per-row leaf matvec ----------------
__global__ __launch_bounds__(256) void k3_leaf(
    const unsigned short* __restrict__ feat, const int* __restrict__ choices,
    const float* __restrict__ Wl, const unsigned short* __restrict__ Wlb,
    const float* __restrict__ blv, float* __restrict__ out)
{
    const int t = threadIdx.x, wv = t >> 6, l = t & 63, g = l >> 4, i = l & 15;
    const int row = blockIdx.x * 16 + wv * 4 + g;
    const int leaf = choices[row];

    ushort8v f0 = *(const ushort8v*)(feat + (size_t)row * H_DIM + i * 16);
    ushort8v f1 = *(const ushort8v*)(feat + (size_t)row * H_DIM + i * 16 + 8);
    float fv[16];
    #pragma unroll
    for (int j = 0; j < 8; ++j) { fv[j] = bf2f(f0[j]); fv[8 + j] = bf2f(f1[j]); }

    float acc[C_CLS];
    #pragma unroll
    for (int c = 0; c < C_CLS; ++c) acc[c] = 0.f;

    if (Wlb) {
        const unsigned short* wp = Wlb + ((size_t)leaf * H_DIM + i * 16) * C_CLS;
        ushort8v wreg[20];
        #pragma unroll
        for (int j = 0; j < 20; ++j) wreg[j] = *(const ushort8v*)(wp + j * 8);
        #pragma unroll
        for (int h = 0; h < 16; ++h) {
            #pragma unroll
            for (int c = 0; c < C_CLS; ++c) {
                int e = h * C_CLS + c;
                acc[c] = fmaf(fv[h], bf2f(wreg[e >> 3][e & 7]), acc[c]);
            }
        }
    } else {
        const float* wp = Wl + ((size_t)leaf * H_DIM + i * 16) * C_CLS;
        #pragma unroll
        for (int h = 0; h < 16; ++h) {
            #pragma unroll
            for (int c = 0; c < C_CLS; ++c)
                acc[c] = fmaf(fv[h], wp[h * C_CLS + c], acc[c]);
        }
    }
    #pragma unroll
    for (int st = 1; st < 16; st <<= 1) {
        #pragma unroll
        for (int c = 0; c < C_CLS; ++c) acc[c] += __shfl_xor(acc[c], st, 64);
    }
    if (i == 0) {
        #pragma unroll
        for (int c = 0; c < C_CLS; ++c)
            out[(size_t)row * C_CLS + c] = acc[c] + blv[leaf * C_CLS + c];
    }
}

// ---------------- launcher ----------------
extern "C" void kernel_launch(void* const* d_in, const int* in_sizes, int n_in,
                              void* d_out, int out_size, void* d_ws, size_t ws_size,
                              hipStream_t stream) {
    if (ws_size < WS_BASE) return;   // loud fail
    const bool use_bf = ws_size >= WS_FULL;

    const float* x   = (const float*)d_in[0];
    const float* Wf  = (const float*)d_in[1];
    const float* bfv = (const float*)d_in[2];
    const float* Wr  = (const float*)d_in[3];
    const float* brv = (const float*)d_in[4];
    const float* Wl  = (const float*)d_in[5];
    const float* blv = (const float*)d_in[6];
    float* out = (float*)d_out;

    char* ws = (char*)d_ws;
    unsigned int*   flagcnt  = (unsigned int*)(ws + O_FLAGCNT);
    int*            choices  = (int*)(ws + O_CHOICES);
    int*            flagrows = (int*)(ws + O_FLAGROWS);
    unsigned short* Wt       = (unsigned short*)(ws + O_WT);
    unsigned short* feat     = (unsigned short*)(ws + O_FEAT);
    unsigned short* Wlb      = use_bf ? (unsigned short*)(ws + O_WLB) : (unsigned short*)0;

    hipLaunchKernelGGL(k0_prep, dim3(NSTEP), dim3(256), 0, stream, Wf, Wr, Wt, flagcnt);
    if (use_bf)
        hipLaunchKernelGGL(k0b_wl, dim3(160), dim3(256), 0, stream, Wl, Wlb);
    hipLaunchKernelGGL(k1_gemm, dim3(B_ROWS / 64), dim3(256), 0, stream,
                       x, Wt, bfv, brv, feat, choices, flagcnt, flagrows);
    hipLaunchKernelGGL(k2_exact, dim3(2048), dim3(256), 0, stream,
                       x, Wr, brv, flagcnt, flagrows, choices);
    hipLaunchKernelGGL(k3_leaf, dim3(B_ROWS / 16), dim3(256), 0, stream,
                       feat, choices, Wl, Wlb, blv, out);
}

// Round 3
// 191.842 us; speedup vs baseline: 1.2124x; 1.0166x over previous
//
#include <hip/hip_runtime.h>
#include <stdint.h>

// ---------------- problem constants ----------------
#define B_ROWS 65536
#define D_IN   784
#define H_DIM  256
#define L_LEAF 64
#define C_CLS  10
#define NSTEP  13            // ceil(784/64) K-steps of 64
#define BTILE  40960         // 320 n * 64 k * 2B per K-step tile
#define GAP_THRESH 0.03f     // ~12 sigma of bf16 logit-gap noise

using f32x4    = __attribute__((ext_vector_type(4))) float;
using bf16x8   = __attribute__((ext_vector_type(8))) short;
using ushort8v = __attribute__((ext_vector_type(8))) unsigned short;
using ushort4v = __attribute__((ext_vector_type(4))) unsigned short;

// ---------------- ws layout (bytes) ----------------
#define O_FLAGCNT  0
#define O_CHOICES  4096
#define O_FLAGROWS (O_CHOICES + B_ROWS * 4)
#define O_WT       (O_FLAGROWS + B_ROWS * 4)
#define O_FEAT     (O_WT + NSTEP * BTILE)
#define O_WLB      (O_FEAT + (size_t)B_ROWS * H_DIM * 2)
#define WS_BASE    O_WLB
#define WS_FULL    (O_WLB + (size_t)L_LEAF * H_DIM * C_CLS * 2)

__device__ __forceinline__ unsigned short f2bf(float f) {
    union { float f; unsigned int u; } c; c.f = f;
    unsigned int u = c.u;
    return (unsigned short)((u + 0x7fffu + ((u >> 16) & 1u)) >> 16);   // RNE
}
__device__ __forceinline__ float bf2f(unsigned short u) {
    union { unsigned int u; float f; } c; c.u = ((unsigned int)u) << 16;
    return c.f;
}

__device__ __forceinline__ void gload_lds16(const void* g, void* l) {
    __builtin_amdgcn_global_load_lds(
        (const __attribute__((address_space(1))) unsigned int*)g,
        (__attribute__((address_space(3))) unsigned int*)l, 16, 0, 0);
}

// ---------------- K0: build swizzled B image. ----------------
// LDS-image byte (ts*40960 + n*128 + c4*16) holds 8 bf16 of column n,
// k = ts*64 + (c4 ^ (n&7))*8 .. +8   (zero-padded past 784).
// grid = 130 blocks x 256 thr, one 16B chunk per thread.
__global__ void k0_prep(const float* __restrict__ Wf, const float* __restrict__ Wr,
                        unsigned short* __restrict__ Wt, unsigned int* __restrict__ flagcnt) {
    if (blockIdx.x == 0 && threadIdx.x == 0) *flagcnt = 0u;
    int id = blockIdx.x * 256 + threadIdx.x;   // 33280 chunks total
    int ts = id / 2560;
    int r  = id % 2560;
    int n  = r % 320;
    int c4 = r / 320;
    int ks = ts * 64 + ((c4 ^ (n & 7)) << 3);
    unsigned short v[8];
    #pragma unroll
    for (int j = 0; j < 8; ++j) {
        int k = ks + j;
        float f = 0.f;
        if (k < D_IN)
            f = (n < H_DIM) ? Wf[(size_t)k * H_DIM + n]
                            : Wr[(size_t)k * L_LEAF + (n - H_DIM)];
        v[j] = f2bf(f);
    }
    *(ushort8v*)((char*)Wt + (size_t)ts * BTILE + (size_t)(n * 8 + c4) * 16) = *(ushort8v*)v;
}

// ---------------- K0b: Wl -> bf16 (optional, if ws permits) ----------------
__global__ void k0b_wl(const float* __restrict__ Wl, unsigned short* __restrict__ Wlb) {
    int i = (blockIdx.x * 256 + threadIdx.x) * 4;
    f32x4 v = *(const f32x4*)(Wl + i);
    ushort4v h; h.x = f2bf(v.x); h.y = f2bf(v.y); h.z = f2bf(v.z); h.w = f2bf(v.w);
    *(ushort4v*)(Wlb + i) = h;
}

// ---------------- K1: fused dual GEMM + argmax/flag ----------------
// grid = 512 x 512 thr (8 waves). Wave = 16 rows x 320 cols; A reg-direct, B via
// global_load_lds double-buffer; 2-phase pipeline. 2 blocks/CU = 4 waves/SIMD.
__global__ __launch_bounds__(512, 4) void k1_gemm(
    const float* __restrict__ x, const unsigned short* __restrict__ Wt,
    const float* __restrict__ bfv, const float* __restrict__ brv,
    unsigned short* __restrict__ feat, int* __restrict__ choices,
    unsigned int* __restrict__ flagcnt, int* __restrict__ flagrows)
{
    __shared__ __align__(16) unsigned short Bl[2][320 * 64];   // 2 x 40 KiB

    const int t = threadIdx.x, w = t >> 6, l = t & 63, q = l >> 4, ic = l & 15;
    const int bm0 = blockIdx.x * 128;
    const float* xrow = x + (size_t)(bm0 + w * 16 + ic) * D_IN;

    f32x4 acc[20];
    #pragma unroll
    for (int i = 0; i < 20; ++i) acc[i] = (f32x4){0.f, 0.f, 0.f, 0.f};

    // per-lane swizzled ds_read offsets (in shorts) for kk=0,1
    const int rb0 = ic * 64 + (((q    ) ^ (ic & 7)) << 3);
    const int rb1 = ic * 64 + (((q + 4) ^ (ic & 7)) << 3);

    // ---- prologue: stage ts=0, load A(ts=0)
    #pragma unroll
    for (int i = 0; i < 5; ++i) {
        int cid = i * 512 + t;
        gload_lds16((const char*)Wt + cid * 16, (char*)&Bl[0][0] + cid * 16);
    }
    f32x4 an[4];
    #pragma unroll
    for (int kk = 0; kk < 2; ++kk) {
        int kg = kk * 32 + q * 8;
        an[2 * kk]     = *(const f32x4*)(xrow + kg);
        an[2 * kk + 1] = *(const f32x4*)(xrow + kg + 4);
    }
    __syncthreads();

    int cur = 0;
    for (int ts = 0; ts < NSTEP; ++ts) {
        // ---- stage next B tile (direct to LDS, stays in flight until barrier)
        if (ts + 1 < NSTEP) {
            const char* src = (const char*)Wt + (size_t)(ts + 1) * BTILE;
            char* dst = (char*)&Bl[cur ^ 1][0];
            #pragma unroll
            for (int i = 0; i < 5; ++i) {
                int cid = i * 512 + t;
                gload_lds16(src + cid * 16, dst + cid * 16);
            }
        }
        f32x4 ac0 = an[0], ac1 = an[1], ac2 = an[2], ac3 = an[3];
        // ---- prefetch A for ts+1 (tail chunks fully OOB are zeroed; B pad is 0 anyway)
        if (ts + 1 < NSTEP) {
            #pragma unroll
            for (int kk = 0; kk < 2; ++kk) {
                int kg = (ts + 1) * 64 + kk * 32 + q * 8;
                if (kg + 8 <= D_IN) {
                    an[2 * kk]     = *(const f32x4*)(xrow + kg);
                    an[2 * kk + 1] = *(const f32x4*)(xrow + kg + 4);
                } else {
                    an[2 * kk]     = (f32x4){0.f, 0.f, 0.f, 0.f};
                    an[2 * kk + 1] = (f32x4){0.f, 0.f, 0.f, 0.f};
                }
            }
        }
        // ---- convert current A to bf16 fragments
        bf16x8 af0, af1;
        #pragma unroll
        for (int j = 0; j < 4; ++j) {
            af0[j]     = (short)f2bf(ac0[j]);
            af0[4 + j] = (short)f2bf(ac1[j]);
            af1[j]     = (short)f2bf(ac2[j]);
            af1[4 + j] = (short)f2bf(ac3[j]);
        }
        // ---- MFMA: 2 kk x 20 nt
        const unsigned short* Bc = &Bl[cur][0];
        #pragma unroll
        for (int nt = 0; nt < 20; ++nt) {
            bf16x8 b = *(const bf16x8*)(Bc + nt * 1024 + rb0);
            acc[nt] = __builtin_amdgcn_mfma_f32_16x16x32_bf16(af0, b, acc[nt], 0, 0, 0);
        }
        #pragma unroll
        for (int nt = 0; nt < 20; ++nt) {
            bf16x8 b = *(const bf16x8*)(Bc + nt * 1024 + rb1);
            acc[nt] = __builtin_amdgcn_mfma_f32_16x16x32_bf16(af1, b, acc[nt], 0, 0, 0);
        }
        __syncthreads();       // drains stage vmcnt + read lgkm; next buf ready
        cur ^= 1;
    }

    // ---- epilogue: features (nt 0..15)
    #pragma unroll
    for (int nt = 0; nt < 16; ++nt) {
        int col = nt * 16 + ic;
        float bias = bfv[col];
        #pragma unroll
        for (int i = 0; i < 4; ++i) {
            int row = bm0 + w * 16 + q * 4 + i;
            float v = acc[nt][i] + bias;
            v = v > 0.f ? v : 0.f;
            feat[(size_t)row * H_DIM + col] = f2bf(v);
        }
    }
    // ---- router (nt 16..19): top-2 + argmax + flag
    #pragma unroll
    for (int i = 0; i < 4; ++i) {
        float m1 = -1e30f, m2 = -1e30f;
        int a1 = 0;
        #pragma unroll
        for (int nt = 16; nt < 20; ++nt) {
            int leaf = (nt - 16) * 16 + ic;
            float v = acc[nt][i] + brv[leaf];
            if (v > m1) { m2 = m1; m1 = v; a1 = leaf; }
            else if (v > m2) { m2 = v; }
        }
        #pragma unroll
        for (int s = 1; s < 16; s <<= 1) {
            float om1 = __shfl_xor(m1, s, 64);
            float om2 = __shfl_xor(m2, s, 64);
            int   oa1 = __shfl_xor(a1, s, 64);
            bool take = (om1 > m1) || (om1 == m1 && oa1 < a1);
            float nm2 = take ? fmaxf(om2, m1) : fmaxf(m2, om1);
            m1 = take ? om1 : m1;
            a1 = take ? oa1 : a1;
            m2 = nm2;
        }
        if (ic == 0) {
            int row = bm0 + w * 16 + q * 4 + i;
            choices[row] = a1;
            if (m1 - m2 < GAP_THRESH) {
                unsigned int idx = atomicAdd(flagcnt, 1u);
                flagrows[idx] = row;
            }
        }
    }
}

// ---------------- K2: exact fp32 router, Wr tiles shared via LDS ----------------
// block = 256 thr (4 waves) handles 4 flagged rows; lane = leaf.
__global__ __launch_bounds__(256) void k2_exact(
    const float* __restrict__ x, const float* __restrict__ Wr,
    const float* __restrict__ brv, const unsigned int* __restrict__ flagcnt,
    const int* __restrict__ flagrows, int* __restrict__ choices)
{
    __shared__ float wl[64 * 64];   // [kk][l]
    __shared__ float xl[4][64];
    const unsigned int cnt = *flagcnt;
    const int t = threadIdx.x, w = t >> 6, l = t & 63;
    for (unsigned int base = blockIdx.x * 4u; base < cnt; base += gridDim.x * 4u) {
        unsigned int ri = base + w;
        int row = (ri < cnt) ? flagrows[ri] : 0;
        const float* xr = x + (size_t)row * D_IN;
        float s0 = 0.f, s1 = 0.f, s2 = 0.f, s3 = 0.f;
        for (int kt = 0; kt < NSTEP; ++kt) {
            int k0 = kt * 64;
            #pragma unroll
            for (int i = 0; i < 4; ++i) {
                int flat = i * 256 + t;
                int kk = flat >> 4, lq = (flat & 15) * 4;
                int kg = k0 + kk;
                f32x4 v = (f32x4){0.f, 0.f, 0.f, 0.f};
                if (kg < D_IN) v = *(const f32x4*)(Wr + (size_t)kg * L_LEAF + lq);
                *(f32x4*)&wl[kk * 64 + lq] = v;
            }
            xl[w][l] = (k0 + l < D_IN) ? xr[k0 + l] : 0.f;
            __syncthreads();
            #pragma unroll
            for (int kk = 0; kk < 64; kk += 4) {
                s0 = fmaf(xl[w][kk    ], wl[(kk    ) * 64 + l], s0);
                s1 = fmaf(xl[w][kk + 1], wl[(kk + 1) * 64 + l], s1);
                s2 = fmaf(xl[w][kk + 2], wl[(kk + 2) * 64 + l], s2);
                s3 = fmaf(xl[w][kk + 3], wl[(kk + 3) * 64 + l], s3);
            }
            __syncthreads();
        }
        float v = (s0 + s1) + (s2 + s3) + brv[l];
        int a = l;
        #pragma unroll
        for (int st = 1; st < 64; st <<= 1) {
            float ov = __shfl_xor(v, st, 64);
            int   oa = __shfl_xor(a, st, 64);
            if (ov > v || (ov == v && oa < a)) { v = ov; a = oa; }
        }
        if (l == 0 && ri < cnt) choices[row] = a;
    }
}

// ---------------- K3: per-row leaf matvec ----------------
__global__ __launch_bounds__(256) void k3_leaf(
    const unsigned short* __restrict__ feat, const int* __restrict__ choices,
    const float* __restrict__ Wl, const unsigned short* __restrict__ Wlb,
    const float* __restrict__ blv, float* __restrict__ out)
{
    const int t = threadIdx.x, wv = t >> 6, l = t & 63, g = l >> 4, i = l & 15;
    const int row = blockIdx.x * 16 + wv * 4 + g;
    const int leaf = choices[row];

    ushort8v f0 = *(const ushort8v*)(feat + (size_t)row * H_DIM + i * 16);
    ushort8v f1 = *(const ushort8v*)(feat + (size_t)row * H_DIM + i * 16 + 8);
    float fv[16];
    #pragma unroll
    for (int j = 0; j < 8; ++j) { fv[j] = bf2f(f0[j]); fv[8 + j] = bf2f(f1[j]); }

    float acc[C_CLS];
    #pragma unroll
    for (int c = 0; c < C_CLS; ++c) acc[c] = 0.f;

    if (Wlb) {
        const unsigned short* wp = Wlb + ((size_t)leaf * H_DIM + i * 16) * C_CLS;
        ushort8v wreg[20];
        #pragma unroll
        for (int j = 0; j < 20; ++j) wreg[j] = *(const ushort8v*)(wp + j * 8);
        #pragma unroll
        for (int h = 0; h < 16; ++h) {
            #pragma unroll
            for (int c = 0; c < C_CLS; ++c) {
                int e = h * C_CLS + c;
                acc[c] = fmaf(fv[h], bf2f(wreg[e >> 3][e & 7]), acc[c]);
            }
        }
    } else {
        const float* wp = Wl + ((size_t)leaf * H_DIM + i * 16) * C_CLS;
        #pragma unroll
        for (int h = 0; h < 16; ++h) {
            #pragma unroll
            for (int c = 0; c < C_CLS; ++c)
                acc[c] = fmaf(fv[h], wp[h * C_CLS + c], acc[c]);
        }
    }
    #pragma unroll
    for (int st = 1; st < 16; st <<= 1) {
        #pragma unroll
        for (int c = 0; c < C_CLS; ++c) acc[c] += __shfl_xor(acc[c], st, 64);
    }
    if (i == 0) {
        #pragma unroll
        for (int c = 0; c < C_CLS; ++c)
            out[(size_t)row * C_CLS + c] = acc[c] + blv[leaf * C_CLS + c];
    }
}

// ---------------- launcher ----------------
extern "C" void kernel_launch(void* const* d_in, const int* in_sizes, int n_in,
                              void* d_out, int out_size, void* d_ws, size_t ws_size,
                              hipStream_t stream) {
    if (ws_size < WS_BASE) return;   // loud fail
    const bool use_bf = ws_size >= WS_FULL;

    const float* x   = (const float*)d_in[0];
    const float* Wf  = (const float*)d_in[1];
    const float* bfv = (const float*)d_in[2];
    const float* Wr  = (const float*)d_in[3];
    const float* brv = (const float*)d_in[4];
    const float* Wl  = (const float*)d_in[5];
    const float* blv = (const float*)d_in[6];
    float* out = (float*)d_out;

    char* ws = (char*)d_ws;
    unsigned int*   flagcnt  = (unsigned int*)(ws + O_FLAGCNT);
    int*            choices  = (int*)(ws + O_CHOICES);
    int*            flagrows = (int*)(ws + O_FLAGROWS);
    unsigned short* Wt       = (unsigned short*)(ws + O_WT);
    unsigned short* feat     = (unsigned short*)(ws + O_FEAT);
    unsigned short* Wlb      = use_bf ? (unsigned short*)(ws + O_WLB) : (unsigned short*)0;

    hipLaunchKernelGGL(k0_prep, dim3(130), dim3(256), 0, stream, Wf, Wr, Wt, flagcnt);
    if (use_bf)
        hipLaunchKernelGGL(k0b_wl, dim3(160), dim3(256), 0, stream, Wl, Wlb);
    hipLaunchKernelGGL(k1_gemm, dim3(B_ROWS / 128), dim3(512), 0, stream,
                       x, Wt, bfv, brv, feat, choices, flagcnt, flagrows);
    hipLaunchKernelGGL(k2_exact, dim3(2048), dim3(256), 0, stream,
                       x, Wr, brv, flagcnt, flagrows, choices);
    hipLaunchKernelGGL(k3_leaf, dim3(B_ROWS / 16), dim3(256), 0, stream,
                       feat, choices, Wl, Wlb, blv, out);
}